// Round 3
// baseline (232.241 us; speedup 1.0000x reference)
//
#include <hip/hip_runtime.h>
#include <math.h>

// HuberEMA: y[t] = y[t-1] + (1-a[c]) * clamp(x[t]-y[t-1], -d, +d); y[0] = x[0]
// B=32, T=2048, C=512 fp32. 16384 independent (b,c) chains -> 256 waves,
// one chain per lane, 256 blocks x 64 threads (1 wave/CU, structural cap).
// Memory-bound (268 MB total, zero reuse): roofline ~43 us @ 6.3 TB/s.
// Latency hidden via UNR=64 double-buffered register prefetch (4 MB in
// flight device-wide) with the reload FUSED into the consume loop so one
// load + one store issues per recurrence step (even VMEM pacing, no
// bursts, shared index arithmetic). Nontemporal on both streams: each
// byte is touched exactly once and the 256 MiB footprint ~= L3 size.
// All register-buffer indexing is compile-time constant (no scratch).

#define TT 2048
#define CCH 512
#define NBATCH 32
#define UNR 64
#define NB (TT / UNR)   // 32 blocks of 64 timesteps

template<bool RELOAD>
__device__ __forceinline__ void consume_block(float (&buf)[UNR], int kblk,
                                              float& yv, float oma, float d,
                                              const float* __restrict__ xp,
                                              float* __restrict__ yp)
{
    const size_t tb = (size_t)kblk * UNR;
    #pragma unroll
    for (int i = 0; i < UNR; ++i) {
        float r = buf[i] - yv;
        if (RELOAD)   // refill this slot with block kblk+2 (same parity)
            buf[i] = __builtin_nontemporal_load(
                         xp + (tb + (size_t)(2 * UNR + i)) * CCH);
        yv += oma * fminf(fmaxf(r, -d), d);
        __builtin_nontemporal_store(yv, yp + (tb + (size_t)i) * CCH);
    }
}

__global__ __launch_bounds__(64, 1)
void huber_ema_kernel(const float* __restrict__ x,
                      const float* __restrict__ logit_alpha,
                      const float* __restrict__ delta,
                      float* __restrict__ y)
{
    const int blk = blockIdx.x;            // 0..255
    const int b   = blk >> 3;              // batch
    const int cc  = blk & 7;               // which 64-wide c chunk
    const int c   = (cc << 6) + threadIdx.x;

    // per-channel alpha (one-time): a = clip(sigmoid(la), 1e-4, 1-1e-4)
    const float la = logit_alpha[c];
    float a = 1.0f / (1.0f + expf(-la));
    a = fminf(fmaxf(a, 1e-4f), 1.0f - 1e-4f);
    const float oma = 1.0f - a;
    const float d = delta[0];

    const size_t base = ((size_t)b * TT) * CCH + (size_t)c;
    const float* __restrict__ xp = x + base;
    float*       __restrict__ yp = y + base;

    float bufA[UNR], bufB[UNR];

    // prologue: block 0 -> A, block 1 -> B
    #pragma unroll
    for (int i = 0; i < UNR; ++i)
        bufA[i] = __builtin_nontemporal_load(xp + (size_t)i * CCH);
    #pragma unroll
    for (int i = 0; i < UNR; ++i)
        bufB[i] = __builtin_nontemporal_load(xp + (size_t)(UNR + i) * CCH);

    // block 0 (from A): t=0 is a straight copy; fused reload of block 2 -> A
    float yv = bufA[0];
    bufA[0] = __builtin_nontemporal_load(xp + (size_t)(2 * UNR) * CCH);
    __builtin_nontemporal_store(yv, yp);
    #pragma unroll
    for (int i = 1; i < UNR; ++i) {
        float r = bufA[i] - yv;
        bufA[i] = __builtin_nontemporal_load(xp + (size_t)(2 * UNR + i) * CCH);
        yv += oma * fminf(fmaxf(r, -d), d);
        __builtin_nontemporal_store(yv, yp + (size_t)i * CCH);
    }

    // steady state: pairs (odd from B, even from A), reload 2 blocks ahead.
    // Blocks 1..28 in pairs; every reload target (k+2 <= 30) is in range.
    for (int k = 1; k + 3 < NB; k += 2) {
        consume_block<true>(bufB, k,     yv, oma, d, xp, yp);
        consume_block<true>(bufA, k + 1, yv, oma, d, xp, yp);
    }
    // tail: block 29 (B) still reloads block 31; blocks 30 (A), 31 (B) don't.
    consume_block<true >(bufB, NB - 3, yv, oma, d, xp, yp);
    consume_block<false>(bufA, NB - 2, yv, oma, d, xp, yp);
    consume_block<false>(bufB, NB - 1, yv, oma, d, xp, yp);
}

extern "C" void kernel_launch(void* const* d_in, const int* in_sizes, int n_in,
                              void* d_out, int out_size, void* d_ws, size_t ws_size,
                              hipStream_t stream) {
    const float* x  = (const float*)d_in[0];
    const float* la = (const float*)d_in[1];
    const float* dl = (const float*)d_in[2];
    float* y = (float*)d_out;

    const int n_blocks = NBATCH * (CCH / 64);  // 256
    huber_ema_kernel<<<dim3(n_blocks), dim3(64), 0, stream>>>(x, la, dl, y);
}